// Round 12
// baseline (97.815 us; speedup 1.0000x reference)
//
#include <hip/hip_runtime.h>
#include <hip/hip_bf16.h>

// Problem constants: B=4, S=2048, D=512, H=8, DK=64
// ws layout (bytes):
//   Xb    @ 0        : 8192*512 bf16        = 8388608
//   Wqkv  @ 8388608  : 1536*512 bf16        = 1572864   (BT: row n = which*512+h*64+dk, col k=d)
//   WoT   @ 9961472  : 512*512 bf16         = 524288    (row n=d, col k=h*64+dk  [permuted concat])
//   Qb    @ 10485760 : 32*2048*64 bf16      = 8388608   ([bh][s][dk], PRE-SCALED by log2(e)/8)
//   Kb    @ 18874368 : 8388608                          ([bh][s][dk])
//   VTb   @ 27262976 : 8388608                          ([bh][dk][s])
//   Oc    @ 35651584 : 8388608                          ([b][s][h*64+dk])
// total 44040192 bytes

typedef __bf16 bf16;
typedef __bf16 bf16x8 __attribute__((ext_vector_type(8)));
typedef __bf16 bf16x4 __attribute__((ext_vector_type(4)));
typedef __bf16 bf16x2 __attribute__((ext_vector_type(2)));
typedef float  f32x4  __attribute__((ext_vector_type(4)));
typedef float  f32x16 __attribute__((ext_vector_type(16)));
typedef unsigned int u32;
typedef u32 u32x4 __attribute__((ext_vector_type(4)));

#define AS1 __attribute__((address_space(1)))
#define AS3 __attribute__((address_space(3)))

__device__ __forceinline__ void async_lds16(const void* gsrc, void* ldst) {
  __builtin_amdgcn_global_load_lds((AS1 const void*)gsrc, (AS3 void*)ldst, 16, 0, 0);
}

// single-instruction exp2 (args bounded: <= THR=8 after max-subtract; -1e30 -> 0)
__device__ __forceinline__ float fexp2(float x) {
  float r;
  asm("v_exp_f32 %0, %1" : "=v"(r) : "v"(x));
  return r;
}

// ---------------- converters ----------------

__global__ __launch_bounds__(256) void k_cvt_x(const float4* __restrict__ X,
                                               bf16x4* __restrict__ Xb) {
  int i = blockIdx.x * 256 + threadIdx.x;
  float4 v = X[i];
  bf16x4 o = { (bf16)v.x, (bf16)v.y, (bf16)v.z, (bf16)v.w };
  Xb[i] = o;
}

// fused weight converter: idx < 786432 -> Wqkv BT; else -> WoT
__global__ __launch_bounds__(256) void k_build_w(const float* __restrict__ Wq,
                                                 const float* __restrict__ Wk,
                                                 const float* __restrict__ Wv,
                                                 const float* __restrict__ Wo,
                                                 bf16* __restrict__ BT,
                                                 bf16* __restrict__ WoT) {
  int idx = blockIdx.x * 256 + threadIdx.x;     // < 1048576
  if (idx < 786432) {
    int n = idx >> 9, d = idx & 511;
    int which = n >> 9, h = (n >> 6) & 7, dk = n & 63;
    const float* W = (which == 0) ? Wq : ((which == 1) ? Wk : Wv);
    BT[idx] = (bf16)W[((h << 9) + d) * 64 + dk];
  } else {
    int i2 = idx - 786432;                      // < 262144
    int d = i2 >> 9, c = i2 & 511;
    int h = c >> 6, dk = c & 63;
    WoT[i2] = (bf16)Wo[(((dk << 3) + h) << 9) + d];
  }
}

// ---------------- GEMM mainloop: 128x128 tile, BK=32, 4 waves, 2-PHASE ----------------
// T3 minimum recipe: double-buffered LDS; STAGE(t+1) at loop top hides L2/L3
// latency under tile-t compute; one vmcnt(0)+barrier per tile.

__device__ __forceinline__ void gemm_tile(const bf16* __restrict__ A,
                                          const bf16* __restrict__ BT,
                                          int K, int m0, int n0,
                                          char* sm, f32x4 acc[4][4]) {
  const int tid = threadIdx.x;
  const int lane = tid & 63, w = tid >> 6;
  const int wm = w >> 1, wn = w & 1;
  const int lr = lane & 15, lg = lane >> 4;
#define GSTAGE(bi, k0) do {                                                        \
    char* base_ = sm + ((bi) << 14);                                               \
    _Pragma("unroll")                                                              \
    for (int i_ = 0; i_ < 2; ++i_) {                                               \
      int off_ = i_ * 256 + tid;                                                   \
      int row_ = off_ >> 2, cb_ = (off_ & 3) << 4;                                 \
      async_lds16((const char*)(A  + (m0 + row_) * K + (k0)) + cb_,                \
                  base_ + off_ * 16);                                              \
      async_lds16((const char*)(BT + (n0 + row_) * K + (k0)) + cb_,                \
                  base_ + 8192 + off_ * 16);                                       \
    }                                                                              \
  } while (0)
  const int NT = K >> 5;
  GSTAGE(0, 0);
  asm volatile("s_waitcnt vmcnt(0)" ::: "memory");
  __builtin_amdgcn_s_barrier();
  __builtin_amdgcn_sched_barrier(0);
  for (int t = 0; t < NT; ++t) {
    char* cb = sm + ((t & 1) << 14);
    if (t + 1 < NT) GSTAGE((t + 1) & 1, (t + 1) << 5);
    bf16x8 af[4], bfr[4];
    #pragma unroll
    for (int u = 0; u < 4; ++u) {
      af[u]  = *(const bf16x8*)(cb +        ((wm * 64 + u * 16 + lr) * 32 + 8 * lg) * 2);
      bfr[u] = *(const bf16x8*)(cb + 8192 + ((wn * 64 + u * 16 + lr) * 32 + 8 * lg) * 2);
    }
    __builtin_amdgcn_s_setprio(1);
    #pragma unroll
    for (int am = 0; am < 4; ++am)
      #pragma unroll
      for (int bn = 0; bn < 4; ++bn)
        acc[am][bn] = __builtin_amdgcn_mfma_f32_16x16x32_bf16(af[am], bfr[bn], acc[am][bn], 0, 0, 0);
    __builtin_amdgcn_s_setprio(0);
    if (t + 1 < NT) {
      asm volatile("s_waitcnt vmcnt(0)" ::: "memory");
      __builtin_amdgcn_s_barrier();
      __builtin_amdgcn_sched_barrier(0);
    }
  }
#undef GSTAGE
}

__global__ __launch_bounds__(256) void k_gemm_qkv(const bf16* __restrict__ A,
                                                  const bf16* __restrict__ BT,
                                                  bf16* __restrict__ Qb,
                                                  bf16* __restrict__ Kb,
                                                  bf16* __restrict__ VTb) {
  __shared__ char sm[32768];
  const int m0 = blockIdx.y * 128, n0 = blockIdx.x * 128;
  f32x4 acc[4][4];
  #pragma unroll
  for (int a = 0; a < 4; ++a)
    #pragma unroll
    for (int b = 0; b < 4; ++b) { f32x4 z = {0.f,0.f,0.f,0.f}; acc[a][b] = z; }
  gemm_tile(A, BT, 512, m0, n0, sm, acc);
  const int lane = threadIdx.x & 63, w = threadIdx.x >> 6;
  const int wm = w >> 1, wn = w & 1, lr = lane & 15, lg = lane >> 4;
  const float qsc = 0.1803368801f;  // log2(e)/sqrt(64), folded into Q
  #pragma unroll
  for (int am = 0; am < 4; ++am)
    #pragma unroll
    for (int bn = 0; bn < 4; ++bn)
      #pragma unroll
      for (int r = 0; r < 4; ++r) {
        int m = m0 + wm * 64 + am * 16 + 4 * lg + r;
        int n = n0 + wn * 64 + bn * 16 + lr;
        int b = m >> 11, s = m & 2047;
        int which = n >> 9, h = (n >> 6) & 7, dk = n & 63;
        int bh = (b << 3) + h;
        float x = acc[am][bn][r];
        if (which == 0)      Qb[((bh << 11) + s) * 64 + dk] = (bf16)(x * qsc);
        else if (which == 1) Kb[((bh << 11) + s) * 64 + dk] = (bf16)x;
        else                 VTb[((bh << 6) + dk) * 2048 + s] = (bf16)x;
      }
}

__global__ __launch_bounds__(256) void k_gemm_out(const bf16* __restrict__ A,
                                                  const bf16* __restrict__ BT,
                                                  float* __restrict__ C) {
  __shared__ char sm[32768];
  const int m0 = blockIdx.y * 128, n0 = blockIdx.x * 128;
  f32x4 acc[4][4];
  #pragma unroll
  for (int a = 0; a < 4; ++a)
    #pragma unroll
    for (int b = 0; b < 4; ++b) { f32x4 z = {0.f,0.f,0.f,0.f}; acc[a][b] = z; }
  gemm_tile(A, BT, 512, m0, n0, sm, acc);
  const int lane = threadIdx.x & 63, w = threadIdx.x >> 6;
  const int wm = w >> 1, wn = w & 1, lr = lane & 15, lg = lane >> 4;
  #pragma unroll
  for (int am = 0; am < 4; ++am)
    #pragma unroll
    for (int bn = 0; bn < 4; ++bn)
      #pragma unroll
      for (int r = 0; r < 4; ++r) {
        int m = m0 + wm * 64 + am * 16 + 4 * lg + r;
        int n = n0 + wn * 64 + bn * 16 + lr;
        C[(m << 9) + n] = acc[am][bn][r];
      }
}

// ---------------- causal flash attention: q-split, LDS-staged K/V, 2-wave blocks ----------------
// Round-12 geometry: block = 2 waves x 32 q-rows (64 rows) of one (b,h); grid 1024
// = 4 blocks/CU (vs r11's 512 = 2/CU where the long+short pairing left CUs with a
// single 4-wave block for most of the kernel -> 12% occupancy). Dispatch gives each
// CU's 4 resident blocks a CONSTANT tile-sum (qt per group g of 32 bids:
// 31-g / g-8 / 39-g / g-16 -> per-CU sum 66) for uniform drain.
// Per-wave body identical to r10/r11 (proven): K/V tile (KVBLK=64, 16KB) double-
// buffered in 32KB LDS, staged via global_load_lds (linear dest + source-XOR +
// read-XOR, rule #21); private per-wave online softmax; no cross-wave combine.
// QK^T: mfma(A=K, B=Q) -> S^T (lane q=l31); PV: mfma(A=V^T, B=P) -> O^T.
// Q pre-scaled by log2(e)/8 -> P = exp2(s - m).
// C/D map (32x32): col = lane&31, row = (reg&3) + 8*(reg>>2) + 4*(lane>>5).

__device__ __forceinline__ void attn_stage(char* base, const bf16* Kh, const bf16* Vh,
                                           int tb, int tid) {
  #pragma unroll
  for (int k = 0; k < 4; ++k) {        // K slots 0..511 (128 threads x 4)
    int s = tid + (k << 7);
    int row = s >> 3, g = s & 7;
    async_lds16((const void*)(Kh + ((tb + row) << 6) + ((g ^ (row & 7)) << 3)),
                base + s * 16);
  }
  #pragma unroll
  for (int k = 0; k < 4; ++k) {        // V slots 0..511 (dv-major)
    int s = tid + (k << 7);
    int row = s >> 3, g = s & 7;
    async_lds16((const void*)(Vh + (row << 11) + tb + ((g ^ (row & 7)) << 3)),
                base + 8192 + s * 16);
  }
}

__global__ __launch_bounds__(128, 2) void k_attn7(const bf16* __restrict__ Qb,
                                                  const bf16* __restrict__ Kb,
                                                  const bf16* __restrict__ VTb,
                                                  bf16* __restrict__ Oc) {
  __shared__ char sm[32768];
  const int tid = threadIdx.x, lane = tid & 63, wv = tid >> 6;
  const int l31 = lane & 31, hi = lane >> 5;
  const int bid = blockIdx.x;
  const int g = bid >> 5, bh = bid & 31;
  const int qt = (g < 8) ? 31 - g : (g < 16) ? g - 8 : (g < 24) ? 39 - g : g - 16;
  const int b = bh >> 3, h = bh & 7;
  const int q0 = qt << 6;
  const int wq0 = q0 + (wv << 5);                // this wave's first q-row
  const bf16* Qh = Qb  + ((size_t)bh << 17);
  const bf16* Kh = Kb  + ((size_t)bh << 17);
  const bf16* Vh = VTb + ((size_t)bh << 17);

  bf16x8 qf[4];
  #pragma unroll
  for (int kd = 0; kd < 4; ++kd)
    qf[kd] = *(const bf16x8*)(Qh + ((wq0 + l31) << 6) + kd * 16 + 8 * hi);

  f32x16 o0, o1;
  #pragma unroll
  for (int r = 0; r < 16; ++r) { o0[r] = 0.f; o1[r] = 0.f; }
  float m_run = -3e38f, lsum = 0.f;

  const int NT = qt + 1;                         // tiles cover kv [0, q0+64)
  const int swz = l31 & 7;                       // row&7 for all this lane's reads

  attn_stage(sm, Kh, Vh, 0, tid);

  for (int t = 0; t < NT; ++t) {
    const int tb = t << 6;
    char* cb = sm + ((t & 1) << 14);
    __syncthreads();                             // drains vmcnt: buf[t&1] ready
    if (t + 1 < NT)
      attn_stage(sm + (((t + 1) & 1) << 14), Kh, Vh, (t + 1) << 6, tid);

    // QK^T from K LDS: two 32-kv halves
    f32x16 sA, sB;
    #pragma unroll
    for (int r = 0; r < 16; ++r) { sA[r] = 0.f; sB[r] = 0.f; }
    {
      bf16x8 kf[4];
      #pragma unroll
      for (int kd = 0; kd < 4; ++kd)
        kf[kd] = *(const bf16x8*)(cb + l31 * 128 + ((((kd << 1) + hi) ^ swz) << 4));
      __builtin_amdgcn_s_setprio(1);
      #pragma unroll
      for (int kd = 0; kd < 4; ++kd)
        sA = __builtin_amdgcn_mfma_f32_32x32x16_bf16(kf[kd], qf[kd], sA, 0, 0, 0);
      __builtin_amdgcn_s_setprio(0);
      #pragma unroll
      for (int kd = 0; kd < 4; ++kd)
        kf[kd] = *(const bf16x8*)(cb + (32 + l31) * 128 + ((((kd << 1) + hi) ^ swz) << 4));
      __builtin_amdgcn_s_setprio(1);
      #pragma unroll
      for (int kd = 0; kd < 4; ++kd)
        sB = __builtin_amdgcn_mfma_f32_32x32x16_bf16(kf[kd], qf[kd], sB, 0, 0, 0);
      __builtin_amdgcn_s_setprio(0);
    }

    const int sg = wq0 + l31;
    // causal mask (only the diagonal tile t == qt)
    if (tb + 63 > wq0) {
      #pragma unroll
      for (int r = 0; r < 16; ++r) {
        int rk = tb + (r & 3) + 8 * (r >> 2) + 4 * hi;
        sA[r] = (rk > sg)      ? -1e30f : sA[r];
        sB[r] = (rk + 32 > sg) ? -1e30f : sB[r];
      }
    }
    // row max: tree + one cross-half exchange
    float tv[16];
    #pragma unroll
    for (int r = 0; r < 16; ++r) tv[r] = fmaxf(sA[r], sB[r]);
    float m0_ = fmaxf(tv[0], tv[1]),  m1_ = fmaxf(tv[2], tv[3]);
    float m2_ = fmaxf(tv[4], tv[5]),  m3_ = fmaxf(tv[6], tv[7]);
    float m4_ = fmaxf(tv[8], tv[9]),  m5_ = fmaxf(tv[10], tv[11]);
    float m6_ = fmaxf(tv[12], tv[13]), m7_ = fmaxf(tv[14], tv[15]);
    float tmax = fmaxf(fmaxf(fmaxf(m0_, m1_), fmaxf(m2_, m3_)),
                       fmaxf(fmaxf(m4_, m5_), fmaxf(m6_, m7_)));
    float tms = fmaxf(tmax, __shfl_xor(tmax, 32));
    // defer-max rescale (T13, THR=8 in exp2 domain)
    if (!__all(tms <= m_run + 8.f)) {
      float mn = fmaxf(m_run, tms);
      float fac = fexp2(m_run - mn);
      #pragma unroll
      for (int r = 0; r < 16; ++r) { o0[r] *= fac; o1[r] *= fac; }
      lsum *= fac;
      m_run = mn;
    }
    // P = exp2(s - m) in place
    #pragma unroll
    for (int r = 0; r < 16; ++r) sA[r] = fexp2(sA[r] - m_run);
    #pragma unroll
    for (int r = 0; r < 16; ++r) sB[r] = fexp2(sB[r] - m_run);
    // row sum
    float a0 = (sA[0]+sB[0]) + (sA[1]+sB[1]),   a1 = (sA[2]+sB[2]) + (sA[3]+sB[3]);
    float a2 = (sA[4]+sB[4]) + (sA[5]+sB[5]),   a3 = (sA[6]+sB[6]) + (sA[7]+sB[7]);
    float a4 = (sA[8]+sB[8]) + (sA[9]+sB[9]),   a5 = (sA[10]+sB[10]) + (sA[11]+sB[11]);
    float a6 = (sA[12]+sB[12]) + (sA[13]+sB[13]), a7 = (sA[14]+sB[14]) + (sA[15]+sB[15]);
    float rs = ((a0 + a1) + (a2 + a3)) + ((a4 + a5) + (a6 + a7));
    lsum += rs + __shfl_xor(rs, 32);

    // per 32-kv half: pack P, permlane -> B-frags; PV from V LDS
    #pragma unroll
    for (int j = 0; j < 2; ++j) {
      u32 pk_[8];
      #pragma unroll
      for (int i = 0; i < 8; ++i) {
        float plo = j ? sB[2 * i] : sA[2 * i];
        float phi = j ? sB[2 * i + 1] : sA[2 * i + 1];
        bf16x2 pr = { (bf16)plo, (bf16)phi };
        pk_[i] = __builtin_bit_cast(u32, pr);
      }
      asm volatile("v_permlane32_swap_b32 %0, %1" : "+v"(pk_[0]), "+v"(pk_[2]));
      asm volatile("v_permlane32_swap_b32 %0, %1" : "+v"(pk_[1]), "+v"(pk_[3]));
      asm volatile("v_permlane32_swap_b32 %0, %1" : "+v"(pk_[4]), "+v"(pk_[6]));
      asm volatile("v_permlane32_swap_b32 %0, %1" : "+v"(pk_[5]), "+v"(pk_[7]));
      u32x4 w0 = { pk_[0], pk_[1], pk_[2], pk_[3] };
      u32x4 w1 = { pk_[4], pk_[5], pk_[6], pk_[7] };
      bf16x8 pb0 = __builtin_bit_cast(bf16x8, w0);
      bf16x8 pb1 = __builtin_bit_cast(bf16x8, w1);
      // V^T A-frags from LDS: dv = dvt*32+l31, 16B-group gg = j*4 + ks*2 + hi
      const char* vb = cb + 8192;
      bf16x8 v00 = *(const bf16x8*)(vb + l31 * 128        + ((((j << 2) + hi) ^ swz) << 4));
      bf16x8 v01 = *(const bf16x8*)(vb + l31 * 128        + ((((j << 2) + 2 + hi) ^ swz) << 4));
      bf16x8 v10 = *(const bf16x8*)(vb + (32 + l31) * 128 + ((((j << 2) + hi) ^ swz) << 4));
      bf16x8 v11 = *(const bf16x8*)(vb + (32 + l31) * 128 + ((((j << 2) + 2 + hi) ^ swz) << 4));
      __builtin_amdgcn_s_setprio(1);
      o0 = __builtin_amdgcn_mfma_f32_32x32x16_bf16(v00, pb0, o0, 0, 0, 0);
      o0 = __builtin_amdgcn_mfma_f32_32x32x16_bf16(v01, pb1, o0, 0, 0, 0);
      o1 = __builtin_amdgcn_mfma_f32_32x32x16_bf16(v10, pb0, o1, 0, 0, 0);
      o1 = __builtin_amdgcn_mfma_f32_32x32x16_bf16(v11, pb1, o1, 0, 0, 0);
      __builtin_amdgcn_s_setprio(0);
    }
  }

  // epilogue: per-wave normalize and coalesced write (no cross-wave combine)
  float rn = 1.f / lsum;
  const int sg = wq0 + l31;
  bf16* Orow = Oc + (((size_t)((b << 11) + sg)) << 9) + (h << 6);
  #pragma unroll
  for (int gq = 0; gq < 4; ++gq) {
    bf16x4 v0, v1;
    #pragma unroll
    for (int i = 0; i < 4; ++i) {
      v0[i] = (bf16)(o0[4 * gq + i] * rn);
      v1[i] = (bf16)(o1[4 * gq + i] * rn);
    }
    *(bf16x4*)(Orow + 4 * hi + 8 * gq)      = v0;
    *(bf16x4*)(Orow + 32 + 4 * hi + 8 * gq) = v1;
  }
}

// ---------------- launch ----------------

extern "C" void kernel_launch(void* const* d_in, const int* in_sizes, int n_in,
                              void* d_out, int out_size, void* d_ws, size_t ws_size,
                              hipStream_t stream) {
  (void)in_sizes; (void)n_in; (void)out_size; (void)ws_size;
  const float* X  = (const float*)d_in[0];
  const float* Wq = (const float*)d_in[1];
  const float* Wk = (const float*)d_in[2];
  const float* Wv = (const float*)d_in[3];
  const float* Wo = (const float*)d_in[4];
  float* out = (float*)d_out;
  char* ws = (char*)d_ws;
  bf16* Xb   = (bf16*)(ws);
  bf16* Wqkv = (bf16*)(ws + 8388608);
  bf16* WoT  = (bf16*)(ws + 9961472);
  bf16* Qb   = (bf16*)(ws + 10485760);
  bf16* Kb   = (bf16*)(ws + 18874368);
  bf16* VTb  = (bf16*)(ws + 27262976);
  bf16* Oc   = (bf16*)(ws + 35651584);

  k_cvt_x<<<4096, 256, 0, stream>>>((const float4*)X, (bf16x4*)Xb);
  k_build_w<<<4096, 256, 0, stream>>>(Wq, Wk, Wv, Wo, Wqkv, WoT);
  k_gemm_qkv<<<dim3(12, 64), 256, 0, stream>>>(Xb, Wqkv, Qb, Kb, VTb);
  k_attn7<<<1024, 128, 0, stream>>>(Qb, Kb, VTb, Oc);
  k_gemm_out<<<dim3(4, 64), 256, 0, stream>>>(Oc, WoT, out);
}

// Round 13
// 97.515 us; speedup vs baseline: 1.0031x; 1.0031x over previous
//
#include <hip/hip_runtime.h>
#include <hip/hip_bf16.h>

// Problem constants: B=4, S=2048, D=512, H=8, DK=64
// ws layout (bytes):
//   Xb    @ 0        : 8192*512 bf16        = 8388608
//   Wqkv  @ 8388608  : 1536*512 bf16        = 1572864
//   WoT   @ 9961472  : 512*512 bf16         = 524288
//   Qb    @ 10485760 : 8388608   ([bh][s][dk], PRE-SCALED by log2(e)/8)
//   Kb    @ 18874368 : 8388608   ([bh][s][dk])
//   VTb   @ 27262976 : 8388608   ([bh][dk][s])
//   Oc    @ 35651584 : 8388608   ([b][s][h*64+dk])
//   Opart @ 44040192 : 1024*128*64 f32 = 33554432   (per-unit partial O^T)
//   Mpart @ 77594624 : 1024*128 f32 = 524288
//   Lpart @ 78118912 : 524288
// total 78643200

typedef __bf16 bf16;
typedef __bf16 bf16x8 __attribute__((ext_vector_type(8)));
typedef __bf16 bf16x4 __attribute__((ext_vector_type(4)));
typedef __bf16 bf16x2 __attribute__((ext_vector_type(2)));
typedef float  f32x4  __attribute__((ext_vector_type(4)));
typedef float  f32x16 __attribute__((ext_vector_type(16)));
typedef unsigned int u32;
typedef u32 u32x4 __attribute__((ext_vector_type(4)));

#define AS1 __attribute__((address_space(1)))
#define AS3 __attribute__((address_space(3)))

__device__ __forceinline__ void async_lds16(const void* gsrc, void* ldst) {
  __builtin_amdgcn_global_load_lds((AS1 const void*)gsrc, (AS3 void*)ldst, 16, 0, 0);
}

// single-instruction exp2 (args bounded above by THR=8; very-negative -> 0)
__device__ __forceinline__ float fexp2(float x) {
  float r;
  asm("v_exp_f32 %0, %1" : "=v"(r) : "v"(x));
  return r;
}

// ---------------- converters ----------------

__global__ __launch_bounds__(256) void k_cvt_x(const float4* __restrict__ X,
                                               bf16x4* __restrict__ Xb) {
  int i = blockIdx.x * 256 + threadIdx.x;
  float4 v = X[i];
  bf16x4 o = { (bf16)v.x, (bf16)v.y, (bf16)v.z, (bf16)v.w };
  Xb[i] = o;
}

__global__ __launch_bounds__(256) void k_build_w(const float* __restrict__ Wq,
                                                 const float* __restrict__ Wk,
                                                 const float* __restrict__ Wv,
                                                 const float* __restrict__ Wo,
                                                 bf16* __restrict__ BT,
                                                 bf16* __restrict__ WoT) {
  int idx = blockIdx.x * 256 + threadIdx.x;     // < 1048576
  if (idx < 786432) {
    int n = idx >> 9, d = idx & 511;
    int which = n >> 9, h = (n >> 6) & 7, dk = n & 63;
    const float* W = (which == 0) ? Wq : ((which == 1) ? Wk : Wv);
    BT[idx] = (bf16)W[((h << 9) + d) * 64 + dk];
  } else {
    int i2 = idx - 786432;
    int d = i2 >> 9, c = i2 & 511;
    int h = c >> 6, dk = c & 63;
    WoT[i2] = (bf16)Wo[(((dk << 3) + h) << 9) + d];
  }
}

// ---------------- GEMM mainloop: 128x128 tile, BK=32, 4 waves, 2-PHASE ----------------

__device__ __forceinline__ void gemm_tile(const bf16* __restrict__ A,
                                          const bf16* __restrict__ BT,
                                          int K, int m0, int n0,
                                          char* sm, f32x4 acc[4][4]) {
  const int tid = threadIdx.x;
  const int lane = tid & 63, w = tid >> 6;
  const int wm = w >> 1, wn = w & 1;
  const int lr = lane & 15, lg = lane >> 4;
#define GSTAGE(bi, k0) do {                                                        \
    char* base_ = sm + ((bi) << 14);                                               \
    _Pragma("unroll")                                                              \
    for (int i_ = 0; i_ < 2; ++i_) {                                               \
      int off_ = i_ * 256 + tid;                                                   \
      int row_ = off_ >> 2, cb_ = (off_ & 3) << 4;                                 \
      async_lds16((const char*)(A  + (m0 + row_) * K + (k0)) + cb_,                \
                  base_ + off_ * 16);                                              \
      async_lds16((const char*)(BT + (n0 + row_) * K + (k0)) + cb_,                \
                  base_ + 8192 + off_ * 16);                                       \
    }                                                                              \
  } while (0)
  const int NT = K >> 5;
  GSTAGE(0, 0);
  asm volatile("s_waitcnt vmcnt(0)" ::: "memory");
  __builtin_amdgcn_s_barrier();
  __builtin_amdgcn_sched_barrier(0);
  for (int t = 0; t < NT; ++t) {
    char* cb = sm + ((t & 1) << 14);
    if (t + 1 < NT) GSTAGE((t + 1) & 1, (t + 1) << 5);
    bf16x8 af[4], bfr[4];
    #pragma unroll
    for (int u = 0; u < 4; ++u) {
      af[u]  = *(const bf16x8*)(cb +        ((wm * 64 + u * 16 + lr) * 32 + 8 * lg) * 2);
      bfr[u] = *(const bf16x8*)(cb + 8192 + ((wn * 64 + u * 16 + lr) * 32 + 8 * lg) * 2);
    }
    __builtin_amdgcn_s_setprio(1);
    #pragma unroll
    for (int am = 0; am < 4; ++am)
      #pragma unroll
      for (int bn = 0; bn < 4; ++bn)
        acc[am][bn] = __builtin_amdgcn_mfma_f32_16x16x32_bf16(af[am], bfr[bn], acc[am][bn], 0, 0, 0);
    __builtin_amdgcn_s_setprio(0);
    if (t + 1 < NT) {
      asm volatile("s_waitcnt vmcnt(0)" ::: "memory");
      __builtin_amdgcn_s_barrier();
      __builtin_amdgcn_sched_barrier(0);
    }
  }
#undef GSTAGE
}

__global__ __launch_bounds__(256) void k_gemm_qkv(const bf16* __restrict__ A,
                                                  const bf16* __restrict__ BT,
                                                  bf16* __restrict__ Qb,
                                                  bf16* __restrict__ Kb,
                                                  bf16* __restrict__ VTb) {
  __shared__ char sm[32768];
  const int m0 = blockIdx.y * 128, n0 = blockIdx.x * 128;
  f32x4 acc[4][4];
  #pragma unroll
  for (int a = 0; a < 4; ++a)
    #pragma unroll
    for (int b = 0; b < 4; ++b) { f32x4 z = {0.f,0.f,0.f,0.f}; acc[a][b] = z; }
  gemm_tile(A, BT, 512, m0, n0, sm, acc);
  const int lane = threadIdx.x & 63, w = threadIdx.x >> 6;
  const int wm = w >> 1, wn = w & 1, lr = lane & 15, lg = lane >> 4;
  const float qsc = 0.1803368801f;  // log2(e)/sqrt(64), folded into Q
  #pragma unroll
  for (int am = 0; am < 4; ++am)
    #pragma unroll
    for (int bn = 0; bn < 4; ++bn)
      #pragma unroll
      for (int r = 0; r < 4; ++r) {
        int m = m0 + wm * 64 + am * 16 + 4 * lg + r;
        int n = n0 + wn * 64 + bn * 16 + lr;
        int b = m >> 11, s = m & 2047;
        int which = n >> 9, h = (n >> 6) & 7, dk = n & 63;
        int bh = (b << 3) + h;
        float x = acc[am][bn][r];
        if (which == 0)      Qb[((bh << 11) + s) * 64 + dk] = (bf16)(x * qsc);
        else if (which == 1) Kb[((bh << 11) + s) * 64 + dk] = (bf16)x;
        else                 VTb[((bh << 6) + dk) * 2048 + s] = (bf16)x;
      }
}

__global__ __launch_bounds__(256) void k_gemm_out(const bf16* __restrict__ A,
                                                  const bf16* __restrict__ BT,
                                                  float* __restrict__ C) {
  __shared__ char sm[32768];
  const int m0 = blockIdx.y * 128, n0 = blockIdx.x * 128;
  f32x4 acc[4][4];
  #pragma unroll
  for (int a = 0; a < 4; ++a)
    #pragma unroll
    for (int b = 0; b < 4; ++b) { f32x4 z = {0.f,0.f,0.f,0.f}; acc[a][b] = z; }
  gemm_tile(A, BT, 512, m0, n0, sm, acc);
  const int lane = threadIdx.x & 63, w = threadIdx.x >> 6;
  const int wm = w >> 1, wn = w & 1, lr = lane & 15, lg = lane >> 4;
  #pragma unroll
  for (int am = 0; am < 4; ++am)
    #pragma unroll
    for (int bn = 0; bn < 4; ++bn)
      #pragma unroll
      for (int r = 0; r < 4; ++r) {
        int m = m0 + wm * 64 + am * 16 + 4 * lg + r;
        int n = n0 + wn * 64 + bn * 16 + lr;
        C[(m << 9) + n] = acc[am][bn][r];
      }
}

// ---------------- causal flash attention: equal-work kv-half units ----------------
// r12 lesson: any fixed q-strip decomposition inherits the causal triangle's
// 16:1 imbalance -> drain leaves ~1 wave/SIMD (3000cy/tile exposed latency).
// This version: each 128-row strip s (NT=2s+2 kv-tiles) splits into TWO EQUAL
// kv-halves of s+1 tiles -> 1024 4-wave units (sizes 1..16, longest-first),
// ~4 blocks/CU sustained. Each unit writes partial (m, l, O^T f32) to ws;
// k_comb merges the 2 halves per strip. Waves with no valid kv in their half
// produce (m=-3e38, l=0, O=0) which combine absorbs (exp2(-3e38-mm)=0).
// Body identical to the proven r11 kernel (LDS-staged K/V, rule-#21 swizzle,
// private per-wave softmax). Block=256 thr; __launch_bounds__(256,4) cap 128.

__device__ __forceinline__ void attn_stage(char* base, const bf16* Kh, const bf16* Vh,
                                           int tb, int tid) {
  #pragma unroll
  for (int k = 0; k < 2; ++k) {        // K slots 0..511
    int s = tid + (k << 8);
    int row = s >> 3, g = s & 7;
    async_lds16((const void*)(Kh + ((tb + row) << 6) + ((g ^ (row & 7)) << 3)),
                base + s * 16);
  }
  #pragma unroll
  for (int k = 0; k < 2; ++k) {        // V slots 0..511 (dv-major)
    int s = tid + (k << 8);
    int row = s >> 3, g = s & 7;
    async_lds16((const void*)(Vh + (row << 11) + tb + ((g ^ (row & 7)) << 3)),
                base + 8192 + s * 16);
  }
}

__global__ __launch_bounds__(256, 4) void k_attn8(const bf16* __restrict__ Qb,
                                                  const bf16* __restrict__ Kb,
                                                  const bf16* __restrict__ VTb,
                                                  float* __restrict__ Opart,
                                                  float* __restrict__ Mpart,
                                                  float* __restrict__ Lpart) {
  __shared__ char sm[32768];
  const int tid = threadIdx.x, lane = tid & 63, wv = tid >> 6;
  const int l31 = lane & 31, hi = lane >> 5;
  const int bid = blockIdx.x;
  const int bh = bid & 31;
  const int u = bid >> 5;                        // 0..31, longest-first
  const int s = 15 - (u >> 1);                   // q-strip 15..0
  const int hf = u & 1;
  const int HL = s + 1;                          // tiles in this kv-half
  const int t0 = hf * HL;
  const int wq0 = (s << 7) + (wv << 5);          // this wave's first q-row
  const bf16* Qh = Qb  + ((size_t)bh << 17);
  const bf16* Kh = Kb  + ((size_t)bh << 17);
  const bf16* Vh = VTb + ((size_t)bh << 17);

  bf16x8 qf[4];
  #pragma unroll
  for (int kd = 0; kd < 4; ++kd)
    qf[kd] = *(const bf16x8*)(Qh + ((wq0 + l31) << 6) + kd * 16 + 8 * hi);

  f32x16 o0, o1;
  #pragma unroll
  for (int r = 0; r < 16; ++r) { o0[r] = 0.f; o1[r] = 0.f; }
  float m_run = -3e38f, lsum = 0.f;

  const int swz = l31 & 7;

  attn_stage(sm, Kh, Vh, t0 << 6, tid);

  for (int tt = 0; tt < HL; ++tt) {
    const int tb = (t0 + tt) << 6;
    char* cb = sm + ((tt & 1) << 14);
    __syncthreads();                             // drains vmcnt: buf ready
    if (tt + 1 < HL)
      attn_stage(sm + (((tt + 1) & 1) << 14), Kh, Vh, (t0 + tt + 1) << 6, tid);
    if (tb > wq0 + 31) continue;                 // fully above diagonal for this wave

    // QK^T from K LDS: two 32-kv halves
    f32x16 sA, sB;
    #pragma unroll
    for (int r = 0; r < 16; ++r) { sA[r] = 0.f; sB[r] = 0.f; }
    {
      bf16x8 kf[4];
      #pragma unroll
      for (int kd = 0; kd < 4; ++kd)
        kf[kd] = *(const bf16x8*)(cb + l31 * 128 + ((((kd << 1) + hi) ^ swz) << 4));
      __builtin_amdgcn_s_setprio(1);
      #pragma unroll
      for (int kd = 0; kd < 4; ++kd)
        sA = __builtin_amdgcn_mfma_f32_32x32x16_bf16(kf[kd], qf[kd], sA, 0, 0, 0);
      __builtin_amdgcn_s_setprio(0);
      #pragma unroll
      for (int kd = 0; kd < 4; ++kd)
        kf[kd] = *(const bf16x8*)(cb + (32 + l31) * 128 + ((((kd << 1) + hi) ^ swz) << 4));
      __builtin_amdgcn_s_setprio(1);
      #pragma unroll
      for (int kd = 0; kd < 4; ++kd)
        sB = __builtin_amdgcn_mfma_f32_32x32x16_bf16(kf[kd], qf[kd], sB, 0, 0, 0);
      __builtin_amdgcn_s_setprio(0);
    }

    const int sg = wq0 + l31;
    if (tb + 63 > wq0) {                         // diagonal band: causal mask
      #pragma unroll
      for (int r = 0; r < 16; ++r) {
        int rk = tb + (r & 3) + 8 * (r >> 2) + 4 * hi;
        sA[r] = (rk > sg)      ? -1e30f : sA[r];
        sB[r] = (rk + 32 > sg) ? -1e30f : sB[r];
      }
    }
    // row max
    float tv[16];
    #pragma unroll
    for (int r = 0; r < 16; ++r) tv[r] = fmaxf(sA[r], sB[r]);
    float m0_ = fmaxf(tv[0], tv[1]),  m1_ = fmaxf(tv[2], tv[3]);
    float m2_ = fmaxf(tv[4], tv[5]),  m3_ = fmaxf(tv[6], tv[7]);
    float m4_ = fmaxf(tv[8], tv[9]),  m5_ = fmaxf(tv[10], tv[11]);
    float m6_ = fmaxf(tv[12], tv[13]), m7_ = fmaxf(tv[14], tv[15]);
    float tmax = fmaxf(fmaxf(fmaxf(m0_, m1_), fmaxf(m2_, m3_)),
                       fmaxf(fmaxf(m4_, m5_), fmaxf(m6_, m7_)));
    float tms = fmaxf(tmax, __shfl_xor(tmax, 32));
    // defer-max rescale (T13, THR=8)
    if (!__all(tms <= m_run + 8.f)) {
      float mn = fmaxf(m_run, tms);
      float fac = fexp2(m_run - mn);
      #pragma unroll
      for (int r = 0; r < 16; ++r) { o0[r] *= fac; o1[r] *= fac; }
      lsum *= fac;
      m_run = mn;
    }
    // P = exp2(s - m) in place
    #pragma unroll
    for (int r = 0; r < 16; ++r) sA[r] = fexp2(sA[r] - m_run);
    #pragma unroll
    for (int r = 0; r < 16; ++r) sB[r] = fexp2(sB[r] - m_run);
    // row sum
    float a0 = (sA[0]+sB[0]) + (sA[1]+sB[1]),   a1 = (sA[2]+sB[2]) + (sA[3]+sB[3]);
    float a2 = (sA[4]+sB[4]) + (sA[5]+sB[5]),   a3 = (sA[6]+sB[6]) + (sA[7]+sB[7]);
    float a4 = (sA[8]+sB[8]) + (sA[9]+sB[9]),   a5 = (sA[10]+sB[10]) + (sA[11]+sB[11]);
    float a6 = (sA[12]+sB[12]) + (sA[13]+sB[13]), a7 = (sA[14]+sB[14]) + (sA[15]+sB[15]);
    float rs = ((a0 + a1) + (a2 + a3)) + ((a4 + a5) + (a6 + a7));
    lsum += rs + __shfl_xor(rs, 32);

    // per 32-kv half: pack P, permlane -> B-frags; PV from V LDS
    #pragma unroll
    for (int j = 0; j < 2; ++j) {
      u32 pk_[8];
      #pragma unroll
      for (int i = 0; i < 8; ++i) {
        float plo = j ? sB[2 * i] : sA[2 * i];
        float phi = j ? sB[2 * i + 1] : sA[2 * i + 1];
        bf16x2 pr = { (bf16)plo, (bf16)phi };
        pk_[i] = __builtin_bit_cast(u32, pr);
      }
      asm volatile("v_permlane32_swap_b32 %0, %1" : "+v"(pk_[0]), "+v"(pk_[2]));
      asm volatile("v_permlane32_swap_b32 %0, %1" : "+v"(pk_[1]), "+v"(pk_[3]));
      asm volatile("v_permlane32_swap_b32 %0, %1" : "+v"(pk_[4]), "+v"(pk_[6]));
      asm volatile("v_permlane32_swap_b32 %0, %1" : "+v"(pk_[5]), "+v"(pk_[7]));
      u32x4 w0 = { pk_[0], pk_[1], pk_[2], pk_[3] };
      u32x4 w1 = { pk_[4], pk_[5], pk_[6], pk_[7] };
      bf16x8 pb0 = __builtin_bit_cast(bf16x8, w0);
      bf16x8 pb1 = __builtin_bit_cast(bf16x8, w1);
      const char* vb = cb + 8192;
      bf16x8 v00 = *(const bf16x8*)(vb + l31 * 128        + ((((j << 2) + hi) ^ swz) << 4));
      bf16x8 v01 = *(const bf16x8*)(vb + l31 * 128        + ((((j << 2) + 2 + hi) ^ swz) << 4));
      bf16x8 v10 = *(const bf16x8*)(vb + (32 + l31) * 128 + ((((j << 2) + hi) ^ swz) << 4));
      bf16x8 v11 = *(const bf16x8*)(vb + (32 + l31) * 128 + ((((j << 2) + 2 + hi) ^ swz) << 4));
      __builtin_amdgcn_s_setprio(1);
      o0 = __builtin_amdgcn_mfma_f32_32x32x16_bf16(v00, pb0, o0, 0, 0, 0);
      o0 = __builtin_amdgcn_mfma_f32_32x32x16_bf16(v01, pb1, o0, 0, 0, 0);
      o1 = __builtin_amdgcn_mfma_f32_32x32x16_bf16(v10, pb0, o1, 0, 0, 0);
      o1 = __builtin_amdgcn_mfma_f32_32x32x16_bf16(v11, pb1, o1, 0, 0, 0);
      __builtin_amdgcn_s_setprio(0);
    }
  }

  // partial epilogue: O^T f32 + (m,l) to ws   (dv(r) = (r&3) + 8*(r>>2) + 4*hi)
  const int prow = (wv << 5) + l31;              // 0..127
  float* Po = Opart + (((size_t)bid) << 13) + (prow << 6);
  #pragma unroll
  for (int g = 0; g < 4; ++g) {
    f32x4 w0 = { o0[4*g], o0[4*g+1], o0[4*g+2], o0[4*g+3] };
    f32x4 w1 = { o1[4*g], o1[4*g+1], o1[4*g+2], o1[4*g+3] };
    *(f32x4*)(Po + (g << 3) + (hi << 2))      = w0;
    *(f32x4*)(Po + 32 + (g << 3) + (hi << 2)) = w1;
  }
  if (!hi) {
    Mpart[(bid << 7) + prow] = m_run;
    Lpart[(bid << 7) + prow] = lsum;
  }
}

// combine the two kv-halves of each strip; write Oc [b][s][h*64+dk]
__global__ __launch_bounds__(256) void k_comb(const float* __restrict__ Opart,
                                              const float* __restrict__ Mpart,
                                              const float* __restrict__ Lpart,
                                              bf16* __restrict__ Oc) {
  const int bid = blockIdx.x;                    // 0..511
  const int bh = bid & 31, cs = bid >> 5;        // cs 0..15
  const int s = 15 - cs;
  const int pu1 = ((cs << 1) | 0) * 32 + bh;
  const int pu2 = ((cs << 1) | 1) * 32 + bh;
  const int b = bh >> 3, h = bh & 7;
  const int t = threadIdx.x;
  const int row = t >> 1;                        // 0..127
  const int dh = (t & 1) << 5;                   // dv 0 or 32
  float m1 = Mpart[(pu1 << 7) + row], m2 = Mpart[(pu2 << 7) + row];
  float l1 = Lpart[(pu1 << 7) + row], l2 = Lpart[(pu2 << 7) + row];
  float mm = fmaxf(m1, m2);
  float f1 = fexp2(m1 - mm), f2 = fexp2(m2 - mm);
  float rn = 1.f / (l1 * f1 + l2 * f2);
  const float* P1 = Opart + (((size_t)pu1) << 13) + (row << 6) + dh;
  const float* P2 = Opart + (((size_t)pu2) << 13) + (row << 6) + dh;
  const int sg = (s << 7) + row;
  bf16* Od = Oc + (((size_t)((b << 11) + sg)) << 9) + (h << 6) + dh;
  #pragma unroll
  for (int g = 0; g < 8; ++g) {
    f32x4 a = *(const f32x4*)(P1 + 4 * g);
    f32x4 c = *(const f32x4*)(P2 + 4 * g);
    bf16x4 o;
    #pragma unroll
    for (int i = 0; i < 4; ++i) o[i] = (bf16)((a[i] * f1 + c[i] * f2) * rn);
    *(bf16x4*)(Od + 4 * g) = o;
  }
}

// ---------------- launch ----------------

extern "C" void kernel_launch(void* const* d_in, const int* in_sizes, int n_in,
                              void* d_out, int out_size, void* d_ws, size_t ws_size,
                              hipStream_t stream) {
  (void)in_sizes; (void)n_in; (void)out_size; (void)ws_size;
  const float* X  = (const float*)d_in[0];
  const float* Wq = (const float*)d_in[1];
  const float* Wk = (const float*)d_in[2];
  const float* Wv = (const float*)d_in[3];
  const float* Wo = (const float*)d_in[4];
  float* out = (float*)d_out;
  char* ws = (char*)d_ws;
  bf16*  Xb    = (bf16*)(ws);
  bf16*  Wqkv  = (bf16*)(ws + 8388608);
  bf16*  WoT   = (bf16*)(ws + 9961472);
  bf16*  Qb    = (bf16*)(ws + 10485760);
  bf16*  Kb    = (bf16*)(ws + 18874368);
  bf16*  VTb   = (bf16*)(ws + 27262976);
  bf16*  Oc    = (bf16*)(ws + 35651584);
  float* Opart = (float*)(ws + 44040192);
  float* Mpart = (float*)(ws + 77594624);
  float* Lpart = (float*)(ws + 78118912);

  k_cvt_x<<<4096, 256, 0, stream>>>((const float4*)X, (bf16x4*)Xb);
  k_build_w<<<4096, 256, 0, stream>>>(Wq, Wk, Wv, Wo, Wqkv, WoT);
  k_gemm_qkv<<<dim3(12, 64), 256, 0, stream>>>(Xb, Wqkv, Qb, Kb, VTb);
  k_attn8<<<1024, 256, 0, stream>>>(Qb, Kb, VTb, Opart, Mpart, Lpart);
  k_comb<<<512, 256, 0, stream>>>(Opart, Mpart, Lpart, Oc);
  k_gemm_out<<<dim3(4, 64), 256, 0, stream>>>(Oc, WoT, out);
}

// Round 14
// 92.177 us; speedup vs baseline: 1.0612x; 1.0579x over previous
//
#include <hip/hip_runtime.h>
#include <hip/hip_bf16.h>

// Problem constants: B=4, S=2048, D=512, H=8, DK=64
// ws layout (bytes):
//   Xb    @ 0        : 8192*512 bf16        = 8388608
//   Wqkv  @ 8388608  : 1536*512 bf16        = 1572864   (BT: row n = which*512+h*64+dk, col k=d)
//   WoT   @ 9961472  : 512*512 bf16         = 524288    (row n=d, col k=h*64+dk  [permuted concat])
//   Qb    @ 10485760 : 8388608   ([bh][s][dk], PRE-SCALED by log2(e)/8)
//   Kb    @ 18874368 : 8388608   ([bh][s][dk])
//   VTb   @ 27262976 : 8388608   ([bh][dk][s])
//   Oc    @ 35651584 : 8388608   ([b][s][h*64+dk])
// total 44040192 bytes

typedef __bf16 bf16;
typedef __bf16 bf16x8 __attribute__((ext_vector_type(8)));
typedef __bf16 bf16x4 __attribute__((ext_vector_type(4)));
typedef __bf16 bf16x2 __attribute__((ext_vector_type(2)));
typedef float  f32x4  __attribute__((ext_vector_type(4)));
typedef float  f32x16 __attribute__((ext_vector_type(16)));
typedef unsigned int u32;
typedef u32 u32x4 __attribute__((ext_vector_type(4)));

#define AS1 __attribute__((address_space(1)))
#define AS3 __attribute__((address_space(3)))

__device__ __forceinline__ void async_lds16(const void* gsrc, void* ldst) {
  __builtin_amdgcn_global_load_lds((AS1 const void*)gsrc, (AS3 void*)ldst, 16, 0, 0);
}

// single-instruction exp2 (args bounded above by THR=8; very-negative -> 0)
__device__ __forceinline__ float fexp2(float x) {
  float r;
  asm("v_exp_f32 %0, %1" : "=v"(r) : "v"(x));
  return r;
}

// ---------------- fused converter: X->bf16, Wq/Wk/Wv->BT, Wo->WoT ----------------

__global__ __launch_bounds__(256) void k_cvt_all(const float4* __restrict__ X4,
                                                 const float* __restrict__ Wq,
                                                 const float* __restrict__ Wk,
                                                 const float* __restrict__ Wv,
                                                 const float* __restrict__ Wo,
                                                 bf16x4* __restrict__ Xb4,
                                                 bf16* __restrict__ BT,
                                                 bf16* __restrict__ WoT) {
  int t = blockIdx.x * 256 + threadIdx.x;       // < 2097152
  if (t < 1048576) {
    float4 v = X4[t];
    bf16x4 o = { (bf16)v.x, (bf16)v.y, (bf16)v.z, (bf16)v.w };
    Xb4[t] = o;
  } else {
    int u = t - 1048576;                        // < 1048576
    if (u < 786432) {
      int n = u >> 9, d = u & 511;
      int which = n >> 9, h = (n >> 6) & 7, dk = n & 63;
      const float* W = (which == 0) ? Wq : ((which == 1) ? Wk : Wv);
      BT[u] = (bf16)W[((h << 9) + d) * 64 + dk];
    } else {
      int i2 = u - 786432;                      // < 262144
      int d = i2 >> 9, c = i2 & 511;
      int h = c >> 6, dk = c & 63;
      WoT[i2] = (bf16)Wo[(((dk << 3) + h) << 9) + d];
    }
  }
}

// ---------------- GEMM mainloop: 128x128 tile, BK=32, 4 waves, 2-PHASE ----------------
// T3 minimum recipe: double-buffered LDS; STAGE(t+1) at loop top hides L2/L3
// latency under tile-t compute; one vmcnt(0)+barrier per tile.

__device__ __forceinline__ void gemm_tile(const bf16* __restrict__ A,
                                          const bf16* __restrict__ BT,
                                          int K, int m0, int n0,
                                          char* sm, f32x4 acc[4][4]) {
  const int tid = threadIdx.x;
  const int lane = tid & 63, w = tid >> 6;
  const int wm = w >> 1, wn = w & 1;
  const int lr = lane & 15, lg = lane >> 4;
#define GSTAGE(bi, k0) do {                                                        \
    char* base_ = sm + ((bi) << 14);                                               \
    _Pragma("unroll")                                                              \
    for (int i_ = 0; i_ < 2; ++i_) {                                               \
      int off_ = i_ * 256 + tid;                                                   \
      int row_ = off_ >> 2, cb_ = (off_ & 3) << 4;                                 \
      async_lds16((const char*)(A  + (m0 + row_) * K + (k0)) + cb_,                \
                  base_ + off_ * 16);                                              \
      async_lds16((const char*)(BT + (n0 + row_) * K + (k0)) + cb_,                \
                  base_ + 8192 + off_ * 16);                                       \
    }                                                                              \
  } while (0)
  const int NT = K >> 5;
  GSTAGE(0, 0);
  asm volatile("s_waitcnt vmcnt(0)" ::: "memory");
  __builtin_amdgcn_s_barrier();
  __builtin_amdgcn_sched_barrier(0);
  for (int t = 0; t < NT; ++t) {
    char* cb = sm + ((t & 1) << 14);
    if (t + 1 < NT) GSTAGE((t + 1) & 1, (t + 1) << 5);
    bf16x8 af[4], bfr[4];
    #pragma unroll
    for (int u = 0; u < 4; ++u) {
      af[u]  = *(const bf16x8*)(cb +        ((wm * 64 + u * 16 + lr) * 32 + 8 * lg) * 2);
      bfr[u] = *(const bf16x8*)(cb + 8192 + ((wn * 64 + u * 16 + lr) * 32 + 8 * lg) * 2);
    }
    __builtin_amdgcn_s_setprio(1);
    #pragma unroll
    for (int am = 0; am < 4; ++am)
      #pragma unroll
      for (int bn = 0; bn < 4; ++bn)
        acc[am][bn] = __builtin_amdgcn_mfma_f32_16x16x32_bf16(af[am], bfr[bn], acc[am][bn], 0, 0, 0);
    __builtin_amdgcn_s_setprio(0);
    if (t + 1 < NT) {
      asm volatile("s_waitcnt vmcnt(0)" ::: "memory");
      __builtin_amdgcn_s_barrier();
      __builtin_amdgcn_sched_barrier(0);
    }
  }
#undef GSTAGE
}

__global__ __launch_bounds__(256) void k_gemm_qkv(const bf16* __restrict__ A,
                                                  const bf16* __restrict__ BT,
                                                  bf16* __restrict__ Qb,
                                                  bf16* __restrict__ Kb,
                                                  bf16* __restrict__ VTb) {
  __shared__ char sm[32768];
  const int m0 = blockIdx.y * 128, n0 = blockIdx.x * 128;
  f32x4 acc[4][4];
  #pragma unroll
  for (int a = 0; a < 4; ++a)
    #pragma unroll
    for (int b = 0; b < 4; ++b) { f32x4 z = {0.f,0.f,0.f,0.f}; acc[a][b] = z; }
  gemm_tile(A, BT, 512, m0, n0, sm, acc);
  const int lane = threadIdx.x & 63, w = threadIdx.x >> 6;
  const int wm = w >> 1, wn = w & 1, lr = lane & 15, lg = lane >> 4;
  const float qsc = 0.1803368801f;  // log2(e)/sqrt(64), folded into Q
  #pragma unroll
  for (int am = 0; am < 4; ++am)
    #pragma unroll
    for (int bn = 0; bn < 4; ++bn)
      #pragma unroll
      for (int r = 0; r < 4; ++r) {
        int m = m0 + wm * 64 + am * 16 + 4 * lg + r;
        int n = n0 + wn * 64 + bn * 16 + lr;
        int b = m >> 11, s = m & 2047;
        int which = n >> 9, h = (n >> 6) & 7, dk = n & 63;
        int bh = (b << 3) + h;
        float x = acc[am][bn][r];
        if (which == 0)      Qb[((bh << 11) + s) * 64 + dk] = (bf16)(x * qsc);
        else if (which == 1) Kb[((bh << 11) + s) * 64 + dk] = (bf16)x;
        else                 VTb[((bh << 6) + dk) * 2048 + s] = (bf16)x;
      }
}

// output GEMM: 128(M)x64(N) tile, grid 512 = 2 blocks/CU (r14: was 128x128 grid
// 256 = 1/CU with zero backfill). Same 2-phase loop; LDS 2 x (8KB A + 4KB B).
__global__ __launch_bounds__(256) void k_gemm_out(const bf16* __restrict__ A,
                                                  const bf16* __restrict__ BT,
                                                  float* __restrict__ C) {
  __shared__ char sm[24576];
  const int m0 = blockIdx.y * 128, n0 = blockIdx.x * 64;
  const int tid = threadIdx.x;
  const int lane = tid & 63, w = tid >> 6;
  const int wm = w >> 1, wn = w & 1;
  const int lr = lane & 15, lg = lane >> 4;
  f32x4 acc[4][2];
  #pragma unroll
  for (int a = 0; a < 4; ++a)
    #pragma unroll
    for (int b = 0; b < 2; ++b) { f32x4 z = {0.f,0.f,0.f,0.f}; acc[a][b] = z; }
#define GSTAGE2(bi, k0) do {                                                       \
    char* base_ = sm + (bi) * 12288;                                               \
    _Pragma("unroll")                                                              \
    for (int i_ = 0; i_ < 2; ++i_) {                                               \
      int off_ = i_ * 256 + tid;                                                   \
      int row_ = off_ >> 2, cb_ = (off_ & 3) << 4;                                 \
      async_lds16((const char*)(A + (m0 + row_) * 512 + (k0)) + cb_,               \
                  base_ + off_ * 16);                                              \
    }                                                                              \
    {                                                                              \
      int off_ = tid;                                                              \
      int row_ = off_ >> 2, cb_ = (off_ & 3) << 4;                                 \
      async_lds16((const char*)(BT + (n0 + row_) * 512 + (k0)) + cb_,              \
                  base_ + 8192 + off_ * 16);                                       \
    }                                                                              \
  } while (0)
  GSTAGE2(0, 0);
  asm volatile("s_waitcnt vmcnt(0)" ::: "memory");
  __builtin_amdgcn_s_barrier();
  __builtin_amdgcn_sched_barrier(0);
  for (int t = 0; t < 16; ++t) {
    char* cb = sm + (t & 1) * 12288;
    if (t + 1 < 16) GSTAGE2((t + 1) & 1, (t + 1) << 5);
    bf16x8 af[4], bfr[2];
    #pragma unroll
    for (int u = 0; u < 4; ++u)
      af[u] = *(const bf16x8*)(cb + ((wm * 64 + u * 16 + lr) * 32 + 8 * lg) * 2);
    #pragma unroll
    for (int v = 0; v < 2; ++v)
      bfr[v] = *(const bf16x8*)(cb + 8192 + ((wn * 32 + v * 16 + lr) * 32 + 8 * lg) * 2);
    __builtin_amdgcn_s_setprio(1);
    #pragma unroll
    for (int am = 0; am < 4; ++am)
      #pragma unroll
      for (int bn = 0; bn < 2; ++bn)
        acc[am][bn] = __builtin_amdgcn_mfma_f32_16x16x32_bf16(af[am], bfr[bn], acc[am][bn], 0, 0, 0);
    __builtin_amdgcn_s_setprio(0);
    if (t + 1 < 16) {
      asm volatile("s_waitcnt vmcnt(0)" ::: "memory");
      __builtin_amdgcn_s_barrier();
      __builtin_amdgcn_sched_barrier(0);
    }
  }
#undef GSTAGE2
  #pragma unroll
  for (int am = 0; am < 4; ++am)
    #pragma unroll
    for (int bn = 0; bn < 2; ++bn)
      #pragma unroll
      for (int r = 0; r < 4; ++r) {
        int m = m0 + wm * 64 + am * 16 + 4 * lg + r;
        int n = n0 + wn * 32 + bn * 16 + lr;
        C[(m << 9) + n] = acc[am][bn][r];
      }
}

// ---------------- causal flash attention: q-split block, LDS-staged shared K/V ----------------
// (byte-identical to round 11 — best measured: 42.7 us)
// Block = 4 waves x 32 DIFFERENT q-rows (128 rows) of one (b,h). KVBLK=64.
// K tile + V^T tile double-buffered in LDS (32KB), staged once per block via
// global_load_lds, shared by all 4 waves; stage(t+1) under tile-t compute.
// Swizzle rule #21: linear LDS dest + source-XOR + read-XOR.
// Private per-wave online softmax (no cross-wave combine).

__device__ __forceinline__ void attn_stage(char* base, const bf16* Kh, const bf16* Vh,
                                           int tb, int tid) {
  #pragma unroll
  for (int k = 0; k < 2; ++k) {        // K slots 0..511
    int s = tid + (k << 8);
    int row = s >> 3, g = s & 7;
    async_lds16((const void*)(Kh + ((tb + row) << 6) + ((g ^ (row & 7)) << 3)),
                base + s * 16);
  }
  #pragma unroll
  for (int k = 0; k < 2; ++k) {        // V slots 0..511 (dv-major)
    int s = tid + (k << 8);
    int row = s >> 3, g = s & 7;
    async_lds16((const void*)(Vh + (row << 11) + tb + ((g ^ (row & 7)) << 3)),
                base + 8192 + s * 16);
  }
}

__global__ __launch_bounds__(256, 2) void k_attn6(const bf16* __restrict__ Qb,
                                                  const bf16* __restrict__ Kb,
                                                  const bf16* __restrict__ VTb,
                                                  bf16* __restrict__ Oc) {
  __shared__ char sm[32768];
  const int tid = threadIdx.x, lane = tid & 63, wv = tid >> 6;
  const int l31 = lane & 31, hi = lane >> 5;
  const int bid = blockIdx.x;
  const int bh = bid & 31;
  const int qb = (bid < 256) ? (15 - (bid >> 5)) : ((bid - 256) >> 5);
  const int b = bh >> 3, h = bh & 7;
  const int q0 = qb << 7;
  const int wq0 = q0 + (wv << 5);                // this wave's first q-row
  const bf16* Qh = Qb  + ((size_t)bh << 17);
  const bf16* Kh = Kb  + ((size_t)bh << 17);
  const bf16* Vh = VTb + ((size_t)bh << 17);

  bf16x8 qf[4];
  #pragma unroll
  for (int kd = 0; kd < 4; ++kd)
    qf[kd] = *(const bf16x8*)(Qh + ((wq0 + l31) << 6) + kd * 16 + 8 * hi);

  f32x16 o0, o1;
  #pragma unroll
  for (int r = 0; r < 16; ++r) { o0[r] = 0.f; o1[r] = 0.f; }
  float m_run = -3e38f, lsum = 0.f;

  const int NT = (qb << 1) + 2;                  // tiles cover kv [0, q0+128)
  const int swz = l31 & 7;                       // row&7 for all this lane's reads

  attn_stage(sm, Kh, Vh, 0, tid);

  for (int t = 0; t < NT; ++t) {
    const int tb = t << 6;
    char* cb = sm + ((t & 1) << 14);
    __syncthreads();                             // drains vmcnt: buf[t&1] ready
    if (t + 1 < NT)
      attn_stage(sm + (((t + 1) & 1) << 14), Kh, Vh, (t + 1) << 6, tid);
    if (tb > wq0 + 31) continue;                 // fully above diagonal for this wave

    // QK^T from K LDS: two 32-kv halves
    f32x16 sA, sB;
    #pragma unroll
    for (int r = 0; r < 16; ++r) { sA[r] = 0.f; sB[r] = 0.f; }
    {
      bf16x8 kf[4];
      #pragma unroll
      for (int kd = 0; kd < 4; ++kd)
        kf[kd] = *(const bf16x8*)(cb + l31 * 128 + ((((kd << 1) + hi) ^ swz) << 4));
      __builtin_amdgcn_s_setprio(1);
      #pragma unroll
      for (int kd = 0; kd < 4; ++kd)
        sA = __builtin_amdgcn_mfma_f32_32x32x16_bf16(kf[kd], qf[kd], sA, 0, 0, 0);
      __builtin_amdgcn_s_setprio(0);
      #pragma unroll
      for (int kd = 0; kd < 4; ++kd)
        kf[kd] = *(const bf16x8*)(cb + (32 + l31) * 128 + ((((kd << 1) + hi) ^ swz) << 4));
      __builtin_amdgcn_s_setprio(1);
      #pragma unroll
      for (int kd = 0; kd < 4; ++kd)
        sB = __builtin_amdgcn_mfma_f32_32x32x16_bf16(kf[kd], qf[kd], sB, 0, 0, 0);
      __builtin_amdgcn_s_setprio(0);
    }

    const int sg = wq0 + l31;
    // causal mask (only tiles overlapping the diagonal band)
    if (tb + 63 > wq0) {
      #pragma unroll
      for (int r = 0; r < 16; ++r) {
        int rk = tb + (r & 3) + 8 * (r >> 2) + 4 * hi;
        sA[r] = (rk > sg)      ? -1e30f : sA[r];
        sB[r] = (rk + 32 > sg) ? -1e30f : sB[r];
      }
    }
    // row max: tree + one cross-half exchange
    float tv[16];
    #pragma unroll
    for (int r = 0; r < 16; ++r) tv[r] = fmaxf(sA[r], sB[r]);
    float m0_ = fmaxf(tv[0], tv[1]),  m1_ = fmaxf(tv[2], tv[3]);
    float m2_ = fmaxf(tv[4], tv[5]),  m3_ = fmaxf(tv[6], tv[7]);
    float m4_ = fmaxf(tv[8], tv[9]),  m5_ = fmaxf(tv[10], tv[11]);
    float m6_ = fmaxf(tv[12], tv[13]), m7_ = fmaxf(tv[14], tv[15]);
    float tmax = fmaxf(fmaxf(fmaxf(m0_, m1_), fmaxf(m2_, m3_)),
                       fmaxf(fmaxf(m4_, m5_), fmaxf(m6_, m7_)));
    float tms = fmaxf(tmax, __shfl_xor(tmax, 32));
    // defer-max rescale (T13, THR=8 in exp2 domain)
    if (!__all(tms <= m_run + 8.f)) {
      float mn = fmaxf(m_run, tms);
      float fac = fexp2(m_run - mn);
      #pragma unroll
      for (int r = 0; r < 16; ++r) { o0[r] *= fac; o1[r] *= fac; }
      lsum *= fac;
      m_run = mn;
    }
    // P = exp2(s - m) in place
    #pragma unroll
    for (int r = 0; r < 16; ++r) sA[r] = fexp2(sA[r] - m_run);
    #pragma unroll
    for (int r = 0; r < 16; ++r) sB[r] = fexp2(sB[r] - m_run);
    // row sum
    float a0 = (sA[0]+sB[0]) + (sA[1]+sB[1]),   a1 = (sA[2]+sB[2]) + (sA[3]+sB[3]);
    float a2 = (sA[4]+sB[4]) + (sA[5]+sB[5]),   a3 = (sA[6]+sB[6]) + (sA[7]+sB[7]);
    float a4 = (sA[8]+sB[8]) + (sA[9]+sB[9]),   a5 = (sA[10]+sB[10]) + (sA[11]+sB[11]);
    float a6 = (sA[12]+sB[12]) + (sA[13]+sB[13]), a7 = (sA[14]+sB[14]) + (sA[15]+sB[15]);
    float rs = ((a0 + a1) + (a2 + a3)) + ((a4 + a5) + (a6 + a7));
    lsum += rs + __shfl_xor(rs, 32);

    // per 32-kv half: pack P, permlane -> B-frags; PV from V LDS
    #pragma unroll
    for (int j = 0; j < 2; ++j) {
      u32 pk_[8];
      #pragma unroll
      for (int i = 0; i < 8; ++i) {
        float plo = j ? sB[2 * i] : sA[2 * i];
        float phi = j ? sB[2 * i + 1] : sA[2 * i + 1];
        bf16x2 pr = { (bf16)plo, (bf16)phi };
        pk_[i] = __builtin_bit_cast(u32, pr);
      }
      asm volatile("v_permlane32_swap_b32 %0, %1" : "+v"(pk_[0]), "+v"(pk_[2]));
      asm volatile("v_permlane32_swap_b32 %0, %1" : "+v"(pk_[1]), "+v"(pk_[3]));
      asm volatile("v_permlane32_swap_b32 %0, %1" : "+v"(pk_[4]), "+v"(pk_[6]));
      asm volatile("v_permlane32_swap_b32 %0, %1" : "+v"(pk_[5]), "+v"(pk_[7]));
      u32x4 w0 = { pk_[0], pk_[1], pk_[2], pk_[3] };
      u32x4 w1 = { pk_[4], pk_[5], pk_[6], pk_[7] };
      bf16x8 pb0 = __builtin_bit_cast(bf16x8, w0);
      bf16x8 pb1 = __builtin_bit_cast(bf16x8, w1);
      // V^T A-frags from LDS: dv = dvt*32+l31, 16B-group gg = j*4 + ks*2 + hi
      const char* vb = cb + 8192;
      bf16x8 v00 = *(const bf16x8*)(vb + l31 * 128        + ((((j << 2) + hi) ^ swz) << 4));
      bf16x8 v01 = *(const bf16x8*)(vb + l31 * 128        + ((((j << 2) + 2 + hi) ^ swz) << 4));
      bf16x8 v10 = *(const bf16x8*)(vb + (32 + l31) * 128 + ((((j << 2) + hi) ^ swz) << 4));
      bf16x8 v11 = *(const bf16x8*)(vb + (32 + l31) * 128 + ((((j << 2) + 2 + hi) ^ swz) << 4));
      __builtin_amdgcn_s_setprio(1);
      o0 = __builtin_amdgcn_mfma_f32_32x32x16_bf16(v00, pb0, o0, 0, 0, 0);
      o0 = __builtin_amdgcn_mfma_f32_32x32x16_bf16(v01, pb1, o0, 0, 0, 0);
      o1 = __builtin_amdgcn_mfma_f32_32x32x16_bf16(v10, pb0, o1, 0, 0, 0);
      o1 = __builtin_amdgcn_mfma_f32_32x32x16_bf16(v11, pb1, o1, 0, 0, 0);
      __builtin_amdgcn_s_setprio(0);
    }
  }

  // epilogue: per-wave normalize and coalesced write (no cross-wave combine)
  float rn = 1.f / lsum;
  const int sg = wq0 + l31;
  bf16* Orow = Oc + (((size_t)((b << 11) + sg)) << 9) + (h << 6);
  #pragma unroll
  for (int g = 0; g < 4; ++g) {
    bf16x4 v0, v1;
    #pragma unroll
    for (int i = 0; i < 4; ++i) {
      v0[i] = (bf16)(o0[4 * g + i] * rn);
      v1[i] = (bf16)(o1[4 * g + i] * rn);
    }
    *(bf16x4*)(Orow + 4 * hi + 8 * g)      = v0;
    *(bf16x4*)(Orow + 32 + 4 * hi + 8 * g) = v1;
  }
}

// ---------------- launch ----------------

extern "C" void kernel_launch(void* const* d_in, const int* in_sizes, int n_in,
                              void* d_out, int out_size, void* d_ws, size_t ws_size,
                              hipStream_t stream) {
  (void)in_sizes; (void)n_in; (void)out_size; (void)ws_size;
  const float* X  = (const float*)d_in[0];
  const float* Wq = (const float*)d_in[1];
  const float* Wk = (const float*)d_in[2];
  const float* Wv = (const float*)d_in[3];
  const float* Wo = (const float*)d_in[4];
  float* out = (float*)d_out;
  char* ws = (char*)d_ws;
  bf16* Xb   = (bf16*)(ws);
  bf16* Wqkv = (bf16*)(ws + 8388608);
  bf16* WoT  = (bf16*)(ws + 9961472);
  bf16* Qb   = (bf16*)(ws + 10485760);
  bf16* Kb   = (bf16*)(ws + 18874368);
  bf16* VTb  = (bf16*)(ws + 27262976);
  bf16* Oc   = (bf16*)(ws + 35651584);

  k_cvt_all<<<8192, 256, 0, stream>>>((const float4*)X, Wq, Wk, Wv, Wo,
                                      (bf16x4*)Xb, Wqkv, WoT);
  k_gemm_qkv<<<dim3(12, 64), 256, 0, stream>>>(Xb, Wqkv, Qb, Kb, VTb);
  k_attn6<<<512, 256, 0, stream>>>(Qb, Kb, VTb, Oc);
  k_gemm_out<<<dim3(8, 64), 256, 0, stream>>>(Oc, WoT, out);
}